// Round 9
// baseline (568.597 us; speedup 1.0000x reference)
//
#include <hip/hip_runtime.h>
#include <math.h>

namespace {

constexpr int kBatch = 32;
constexpr int kTok   = 512;
constexpr int kDim   = 768;
constexpr int kSlots = 64;
constexpr int kSteps = 4;
constexpr int kCls   = 8;
constexpr float kScale = 0.03608439182435161f;  // 1/sqrt(768)
constexpr int kPad   = 40;   // LDS row stride (u16) for 40-pad tiles
constexpr int kPad2  = 36;   // LDS row stride (u16) for write_gate tiles

typedef __attribute__((ext_vector_type(4))) float f32x4;
typedef __attribute__((ext_vector_type(8))) short bf16x8;
typedef __attribute__((ext_vector_type(8))) unsigned short u16x8;
typedef __attribute__((ext_vector_type(4))) unsigned short u16x4;

__device__ __forceinline__ float clipf(float x, float c) { return fminf(fmaxf(x, -c), c); }
__device__ __forceinline__ unsigned short f2bf(float f) {
  unsigned u = __float_as_uint(f);
  return (unsigned short)((u + 0x7fffu + ((u >> 16) & 1u)) >> 16);  // RNE
}
__device__ __forceinline__ float bf2f(unsigned short h) {
  return __uint_as_float(((unsigned)h) << 16);
}

// ---------------- transpose+cvt: Wv, gW -> WvT, gWT (bf16 [out][in]) -----------
__global__ __launch_bounds__(256) void k_prep(
    const float* __restrict__ Wv, const float* __restrict__ gW,
    unsigned short* __restrict__ WvT, unsigned short* __restrict__ gWT)
{
  __shared__ float tile[32][33];
  const int mat = blockIdx.z;
  const float* src = (mat == 0) ? Wv : gW;
  unsigned short* dst = (mat == 0) ? WvT : gWT;
  const int tx = threadIdx.x & 31, ty = threadIdx.x >> 5;
  const int r0 = blockIdx.y * 32, c0 = blockIdx.x * 32;
  #pragma unroll
  for (int q = 0; q < 4; ++q)
    tile[ty + 8*q][tx] = src[(size_t)(r0 + ty + 8*q) * kDim + c0 + tx];
  __syncthreads();
  #pragma unroll
  for (int q = 0; q < 4; ++q)
    dst[(size_t)(c0 + ty + 8*q) * kDim + r0 + tx] = f2bf(tile[tx][ty + 8*q]);
}

// ---------------- WqkT[d][e] = sum_c Wk[d][c] * Wq[e][c]  (NT MFMA, once) ------
__global__ __launch_bounds__(64) void k_wqk(
    const float* __restrict__ Wk, const float* __restrict__ Wq,
    unsigned short* __restrict__ WqkT)
{
  __shared__ unsigned short As[64][kPad];
  __shared__ unsigned short Bs[64][kPad];
  const int lane = threadIdx.x;
  const int m0 = blockIdx.x * 64, n0 = blockIdx.y * 64;
  const int fr = lane & 15, kg = (lane >> 4) << 3, crow = (lane >> 4) << 2;
  f32x4 acc[4][4];
  #pragma unroll
  for (int i = 0; i < 4; ++i)
    #pragma unroll
    for (int j = 0; j < 4; ++j) acc[i][j] = (f32x4)(0.f);
  const float* arow = Wk + (size_t)(m0 + lane) * kDim;
  const float* brow = Wq + (size_t)(n0 + lane) * kDim;
  for (int k0 = 0; k0 < kDim; k0 += 32) {
    unsigned short av[32], bv[32];
    #pragma unroll
    for (int q = 0; q < 8; ++q) {
      float4 a4 = *reinterpret_cast<const float4*>(arow + k0 + 4*q);
      float4 b4 = *reinterpret_cast<const float4*>(brow + k0 + 4*q);
      av[4*q+0]=f2bf(a4.x); av[4*q+1]=f2bf(a4.y); av[4*q+2]=f2bf(a4.z); av[4*q+3]=f2bf(a4.w);
      bv[4*q+0]=f2bf(b4.x); bv[4*q+1]=f2bf(b4.y); bv[4*q+2]=f2bf(b4.z); bv[4*q+3]=f2bf(b4.w);
    }
    #pragma unroll
    for (int h = 0; h < 4; ++h) {
      *reinterpret_cast<u16x8*>(&As[lane][8*h]) = *reinterpret_cast<u16x8*>(&av[8*h]);
      *reinterpret_cast<u16x8*>(&Bs[lane][8*h]) = *reinterpret_cast<u16x8*>(&bv[8*h]);
    }
    __syncthreads();
    bf16x8 a[4], bb[4];
    #pragma unroll
    for (int mt = 0; mt < 4; ++mt) a[mt] = *reinterpret_cast<const bf16x8*>(&As[mt*16 + fr][kg]);
    #pragma unroll
    for (int nt = 0; nt < 4; ++nt) bb[nt] = *reinterpret_cast<const bf16x8*>(&Bs[nt*16 + fr][kg]);
    #pragma unroll
    for (int mt = 0; mt < 4; ++mt)
      #pragma unroll
      for (int nt = 0; nt < 4; ++nt)
        acc[mt][nt] = __builtin_amdgcn_mfma_f32_16x16x32_bf16(a[mt], bb[nt], acc[mt][nt], 0, 0, 0);
    __syncthreads();
  }
  #pragma unroll
  for (int mt = 0; mt < 4; ++mt) {
    const int row = m0 + mt*16 + crow;
    #pragma unroll
    for (int nt = 0; nt < 4; ++nt) {
      const int col = n0 + nt*16 + fr;
      #pragma unroll
      for (int r = 0; r < 4; ++r)
        WqkT[(size_t)(row + r) * kDim + col] = f2bf(acc[mt][nt][r]);
    }
  }
}

// ---------------- M init: f32 + bf16 copies ------------------------------------
__global__ __launch_bounds__(256) void k_minit(
    const float* __restrict__ mi, float* __restrict__ M, unsigned short* __restrict__ Mb)
{
  int i = blockIdx.x * 256 + threadIdx.x;
  constexpr int per = kSlots * kDim / 4;
  float4 v = reinterpret_cast<const float4*>(mi)[i % per];
  reinterpret_cast<float4*>(M)[i] = v;
  u16x4 p; p[0]=f2bf(v.x); p[1]=f2bf(v.y); p[2]=f2bf(v.z); p[3]=f2bf(v.w);
  *reinterpret_cast<u16x4*>(Mb + (size_t)i*4) = p;
}

// ---------------- valid[b] -----------------------------------------------------
__global__ __launch_bounds__(256) void k_valid(const int* __restrict__ mask, float* __restrict__ vf) {
  __shared__ float red[256];
  const int b = blockIdx.x, tid = threadIdx.x;
  float c = 0.f;
  for (int t = tid; t < kTok; t += 256) c += (mask[b*kTok + t] > 0) ? 1.f : 0.f;
  red[tid] = c; __syncthreads();
  for (int off = 128; off > 0; off >>= 1) { if (tid < off) red[tid] += red[tid+off]; __syncthreads(); }
  if (tid == 0) vf[b] = red[0];
}

// ---------------- Qk = x@Wqk, VtT = (x@Wv)^T  (dbuf LDS, 1 barrier/iter) -------
// grid (16384/64=256, 768/128=6), 256 thr = 4 waves
__global__ __launch_bounds__(256) void k_embed_qv(
    const int* __restrict__ ids, const float* __restrict__ tok, const float* __restrict__ pos,
    const unsigned short* __restrict__ WqkT, const unsigned short* __restrict__ WvT,
    unsigned short* __restrict__ Qk, unsigned short* __restrict__ VtT)
{
  __shared__ unsigned short As[2][64][kPad];
  __shared__ unsigned short Bq[2][128][kPad];
  __shared__ unsigned short Bv[2][128][kPad];
  __shared__ int rid[64];
  const int tid = threadIdx.x;
  const int m0 = blockIdx.x * 64, n0 = blockIdx.y * 128;
  if (tid < 64) rid[tid] = ids[m0 + tid];
  const int wave = tid >> 6, lane = tid & 63;
  const int ar = tid >> 2, ac = (tid & 3) << 3;   // A staging: row, 8-col group
  const int br = tid >> 1, bc = (tid & 1) << 4;   // B staging: row, 16-col group
  const int fr = lane & 15, kg = (lane >> 4) << 3, crow = (lane >> 4) << 2;
  f32x4 accq[4][2], accv[4][2];
  #pragma unroll
  for (int i = 0; i < 4; ++i)
    #pragma unroll
    for (int j = 0; j < 2; ++j) { accq[i][j] = (f32x4)(0.f); accv[i][j] = (f32x4)(0.f); }
  __syncthreads();
  const float* tokrow = tok + (size_t)rid[ar] * kDim;
  const float* posrow = pos + (size_t)((m0 + ar) & (kTok - 1)) * kDim;
  const unsigned short* bqrow = WqkT + (size_t)(n0 + br) * kDim;
  const unsigned short* bvrow = WvT  + (size_t)(n0 + br) * kDim;

  float4 tv0, tv1, pv0, pv1;
  u16x8 q0, q1, v0, v1;
  // tile 0 -> regs
  tv0 = *reinterpret_cast<const float4*>(tokrow + ac);
  tv1 = *reinterpret_cast<const float4*>(tokrow + ac + 4);
  pv0 = *reinterpret_cast<const float4*>(posrow + ac);
  pv1 = *reinterpret_cast<const float4*>(posrow + ac + 4);
  q0 = *reinterpret_cast<const u16x8*>(bqrow + bc);
  q1 = *reinterpret_cast<const u16x8*>(bqrow + bc + 8);
  v0 = *reinterpret_cast<const u16x8*>(bvrow + bc);
  v1 = *reinterpret_cast<const u16x8*>(bvrow + bc + 8);
  // stage tile 0 -> buf0
  {
    unsigned short av[8];
    av[0]=f2bf(tv0.x+pv0.x); av[1]=f2bf(tv0.y+pv0.y); av[2]=f2bf(tv0.z+pv0.z); av[3]=f2bf(tv0.w+pv0.w);
    av[4]=f2bf(tv1.x+pv1.x); av[5]=f2bf(tv1.y+pv1.y); av[6]=f2bf(tv1.z+pv1.z); av[7]=f2bf(tv1.w+pv1.w);
    *reinterpret_cast<u16x8*>(&As[0][ar][ac]) = *reinterpret_cast<u16x8*>(&av[0]);
    *reinterpret_cast<u16x8*>(&Bq[0][br][bc])     = q0;
    *reinterpret_cast<u16x8*>(&Bq[0][br][bc + 8]) = q1;
    *reinterpret_cast<u16x8*>(&Bv[0][br][bc])     = v0;
    *reinterpret_cast<u16x8*>(&Bv[0][br][bc + 8]) = v1;
  }
  // tile 1 -> regs
  tv0 = *reinterpret_cast<const float4*>(tokrow + 32 + ac);
  tv1 = *reinterpret_cast<const float4*>(tokrow + 32 + ac + 4);
  pv0 = *reinterpret_cast<const float4*>(posrow + 32 + ac);
  pv1 = *reinterpret_cast<const float4*>(posrow + 32 + ac + 4);
  q0 = *reinterpret_cast<const u16x8*>(bqrow + 32 + bc);
  q1 = *reinterpret_cast<const u16x8*>(bqrow + 32 + bc + 8);
  v0 = *reinterpret_cast<const u16x8*>(bvrow + 32 + bc);
  v1 = *reinterpret_cast<const u16x8*>(bvrow + 32 + bc + 8);
  __syncthreads();

  for (int i = 0; i < 24; ++i) {
    const int cur = i & 1;
    if (i < 23) {
      unsigned short av[8];
      av[0]=f2bf(tv0.x+pv0.x); av[1]=f2bf(tv0.y+pv0.y); av[2]=f2bf(tv0.z+pv0.z); av[3]=f2bf(tv0.w+pv0.w);
      av[4]=f2bf(tv1.x+pv1.x); av[5]=f2bf(tv1.y+pv1.y); av[6]=f2bf(tv1.z+pv1.z); av[7]=f2bf(tv1.w+pv1.w);
      *reinterpret_cast<u16x8*>(&As[cur^1][ar][ac]) = *reinterpret_cast<u16x8*>(&av[0]);
      *reinterpret_cast<u16x8*>(&Bq[cur^1][br][bc])     = q0;
      *reinterpret_cast<u16x8*>(&Bq[cur^1][br][bc + 8]) = q1;
      *reinterpret_cast<u16x8*>(&Bv[cur^1][br][bc])     = v0;
      *reinterpret_cast<u16x8*>(&Bv[cur^1][br][bc + 8]) = v1;
      if (i < 22) {
        const int kn = (i + 2) * 32;
        tv0 = *reinterpret_cast<const float4*>(tokrow + kn + ac);
        tv1 = *reinterpret_cast<const float4*>(tokrow + kn + ac + 4);
        pv0 = *reinterpret_cast<const float4*>(posrow + kn + ac);
        pv1 = *reinterpret_cast<const float4*>(posrow + kn + ac + 4);
        q0 = *reinterpret_cast<const u16x8*>(bqrow + kn + bc);
        q1 = *reinterpret_cast<const u16x8*>(bqrow + kn + bc + 8);
        v0 = *reinterpret_cast<const u16x8*>(bvrow + kn + bc);
        v1 = *reinterpret_cast<const u16x8*>(bvrow + kn + bc + 8);
      }
    }
    bf16x8 a[4], bq[2], bv[2];
    #pragma unroll
    for (int mt = 0; mt < 4; ++mt) a[mt] = *reinterpret_cast<const bf16x8*>(&As[cur][mt*16 + fr][kg]);
    #pragma unroll
    for (int nt = 0; nt < 2; ++nt) {
      bq[nt] = *reinterpret_cast<const bf16x8*>(&Bq[cur][wave*32 + nt*16 + fr][kg]);
      bv[nt] = *reinterpret_cast<const bf16x8*>(&Bv[cur][wave*32 + nt*16 + fr][kg]);
    }
    #pragma unroll
    for (int mt = 0; mt < 4; ++mt)
      #pragma unroll
      for (int nt = 0; nt < 2; ++nt) {
        accq[mt][nt] = __builtin_amdgcn_mfma_f32_16x16x32_bf16(a[mt], bq[nt], accq[mt][nt], 0, 0, 0);
        accv[mt][nt] = __builtin_amdgcn_mfma_f32_16x16x32_bf16(a[mt], bv[nt], accv[mt][nt], 0, 0, 0);
      }
    __syncthreads();
  }
  const int b = m0 >> 9;
  unsigned short* vb = VtT + (size_t)b * kDim * kTok;
  #pragma unroll
  for (int mt = 0; mt < 4; ++mt) {
    const int trow = m0 + mt*16 + crow;
    const int tloc = trow & (kTok - 1);
    #pragma unroll
    for (int nt = 0; nt < 2; ++nt) {
      const int dcol = n0 + wave*32 + nt*16 + fr;
      u16x4 pk;
      #pragma unroll
      for (int r = 0; r < 4; ++r) {
        Qk[(size_t)(trow + r) * kDim + dcol] = f2bf(accq[mt][nt][r]);
        pk[r] = f2bf(accv[mt][nt][r]);
      }
      *reinterpret_cast<u16x4*>(vb + (size_t)dcol * kTok + tloc) = pk;
    }
  }
}

// ---------------- scores = Qk@Mb^T -> masked softmax -> Wt[b][s][t] ------------
// 2 waves, s-split (wave w: s in [w*32, w*32+32)), 32 t per block. grid (16,32)
__global__ __launch_bounds__(128) void k_scores(
    const unsigned short* __restrict__ Qk, const unsigned short* __restrict__ Mb,
    const int* __restrict__ mask, const float* __restrict__ vf,
    unsigned short* __restrict__ Wt)
{
  __shared__ unsigned short As[2][32][kPad];
  __shared__ unsigned short Bs[2][64][kPad];
  __shared__ float xm[2][32];
  __shared__ float xs[2][32];
  const int tid = threadIdx.x;
  const int w = tid >> 6, lane = tid & 63;
  const int b = blockIdx.y, t0 = blockIdx.x * 32;
  const int fr = lane & 15, kg = (lane >> 4) << 3, crow = (lane >> 4) << 2;
  const int srow = tid >> 1, scol = (tid & 1) << 4;
  const bool doA = (tid < 64);
  const unsigned short* qrow = Qk + (size_t)(b*kTok + t0 + (srow & 31)) * kDim + scol;
  const unsigned short* krow = Mb + (size_t)(b*kSlots + srow) * kDim + scol;
  f32x4 acc[2][2];
  #pragma unroll
  for (int i = 0; i < 2; ++i)
    #pragma unroll
    for (int j = 0; j < 2; ++j) acc[i][j] = (f32x4)(0.f);

  u16x8 ra0, ra1, rb0, rb1;
  if (doA) { ra0 = *reinterpret_cast<const u16x8*>(qrow); ra1 = *reinterpret_cast<const u16x8*>(qrow + 8); }
  rb0 = *reinterpret_cast<const u16x8*>(krow); rb1 = *reinterpret_cast<const u16x8*>(krow + 8);
  if (doA) {
    *reinterpret_cast<u16x8*>(&As[0][srow][scol])     = ra0;
    *reinterpret_cast<u16x8*>(&As[0][srow][scol + 8]) = ra1;
  }
  *reinterpret_cast<u16x8*>(&Bs[0][srow][scol])     = rb0;
  *reinterpret_cast<u16x8*>(&Bs[0][srow][scol + 8]) = rb1;
  if (doA) { ra0 = *reinterpret_cast<const u16x8*>(qrow + 32); ra1 = *reinterpret_cast<const u16x8*>(qrow + 40); }
  rb0 = *reinterpret_cast<const u16x8*>(krow + 32); rb1 = *reinterpret_cast<const u16x8*>(krow + 40);
  __syncthreads();

  for (int i = 0; i < 24; ++i) {
    const int cur = i & 1;
    if (i < 23) {
      if (doA) {
        *reinterpret_cast<u16x8*>(&As[cur^1][srow][scol])     = ra0;
        *reinterpret_cast<u16x8*>(&As[cur^1][srow][scol + 8]) = ra1;
      }
      *reinterpret_cast<u16x8*>(&Bs[cur^1][srow][scol])     = rb0;
      *reinterpret_cast<u16x8*>(&Bs[cur^1][srow][scol + 8]) = rb1;
      if (i < 22) {
        const int kn = (i + 2) * 32;
        if (doA) { ra0 = *reinterpret_cast<const u16x8*>(qrow + kn); ra1 = *reinterpret_cast<const u16x8*>(qrow + kn + 8); }
        rb0 = *reinterpret_cast<const u16x8*>(krow + kn); rb1 = *reinterpret_cast<const u16x8*>(krow + kn + 8);
      }
    }
    bf16x8 a[2], bb[2];
    #pragma unroll
    for (int mt = 0; mt < 2; ++mt) a[mt] = *reinterpret_cast<const bf16x8*>(&As[cur][mt*16 + fr][kg]);
    #pragma unroll
    for (int nt = 0; nt < 2; ++nt) bb[nt] = *reinterpret_cast<const bf16x8*>(&Bs[cur][w*32 + nt*16 + fr][kg]);
    #pragma unroll
    for (int mt = 0; mt < 2; ++mt)
      #pragma unroll
      for (int nt = 0; nt < 2; ++nt)
        acc[mt][nt] = __builtin_amdgcn_mfma_f32_16x16x32_bf16(a[mt], bb[nt], acc[mt][nt], 0, 0, 0);
    __syncthreads();
  }
  // clip
  #pragma unroll
  for (int mt = 0; mt < 2; ++mt)
    #pragma unroll
    for (int nt = 0; nt < 2; ++nt)
      #pragma unroll
      for (int r = 0; r < 4; ++r)
        acc[mt][nt][r] = clipf(acc[mt][nt][r] * kScale, 20.f);
  // local (per-wave) softmax stats over its 32 slots
  float lmax[2][4], lsum[2][4];
  #pragma unroll
  for (int mt = 0; mt < 2; ++mt) {
    #pragma unroll
    for (int r = 0; r < 4; ++r) {
      float mx = fmaxf(acc[mt][0][r], acc[mt][1][r]);
      #pragma unroll
      for (int m = 1; m < 16; m <<= 1) mx = fmaxf(mx, __shfl_xor(mx, m, 64));
      float sum = 0.f;
      #pragma unroll
      for (int nt = 0; nt < 2; ++nt) { float e = __expf(acc[mt][nt][r] - mx); acc[mt][nt][r] = e; sum += e; }
      #pragma unroll
      for (int m = 1; m < 16; m <<= 1) sum += __shfl_xor(sum, m, 64);
      lmax[mt][r] = mx; lsum[mt][r] = sum;
      if (fr == 0) {
        const int tl = mt*16 + crow + r;
        xm[w][tl] = mx; xs[w][tl] = sum;
      }
    }
  }
  __syncthreads();
  const float vfb = vf[b];
  unsigned short* wb = Wt + (size_t)b * kSlots * kTok;
  #pragma unroll
  for (int mt = 0; mt < 2; ++mt) {
    const int tbase = t0 + mt*16 + crow;
    #pragma unroll
    for (int r = 0; r < 4; ++r) {
      const int tl = mt*16 + crow + r;
      const float om = xm[w^1][tl], os = xs[w^1][tl];
      const float m = fmaxf(lmax[mt][r], om);
      const float tot = lsum[mt][r] * __expf(lmax[mt][r] - m) + os * __expf(om - m);
      const bool keep = (mask[b*kTok + tbase + r] > 0) || (vfb == 0.f);
      const float fac = keep ? (__expf(lmax[mt][r] - m) / tot) : 0.f;
      #pragma unroll
      for (int nt = 0; nt < 2; ++nt)
        acc[mt][nt][r] *= fac;
    }
    #pragma unroll
    for (int nt = 0; nt < 2; ++nt) {
      const int s = w*32 + nt*16 + fr;
      u16x4 pk;
      #pragma unroll
      for (int r = 0; r < 4; ++r) pk[r] = f2bf(acc[mt][nt][r]);
      *reinterpret_cast<u16x4*>(wb + (size_t)s * kTok + tbase) = pk;
    }
  }
}

// ---------------- write+gate fused, 4-wave K-split ------------------------------
// Each wave: write-GEMM K slice 128 (4 iters) + gate-GEMM K slice 192 (6 iters),
// own dbuf LDS tiles (no intra-loop barriers), then LDS tree-reduce + epilogue.
// grid (12, 32), 256 thr
__global__ __launch_bounds__(256) void k_write_gate(
    const unsigned short* __restrict__ Wt, const unsigned short* __restrict__ VtT,
    const unsigned short* __restrict__ MbIn, const unsigned short* __restrict__ gWT,
    const float* __restrict__ gb, float* __restrict__ M, unsigned short* __restrict__ MbOut)
{
  __shared__ __align__(16) char smem[73728];
  const int tid = threadIdx.x, w = tid >> 6, lane = tid & 63;
  const int b = blockIdx.y, n0 = blockIdx.x * 64;
  const int fr = lane & 15, kg = (lane >> 4) << 3, crow = (lane >> 4) << 2;
  unsigned short* tA0 = (unsigned short*)(smem + w*18432);
  unsigned short* tA1 = (unsigned short*)(smem + w*18432 + 4608);
  unsigned short* tB0 = (unsigned short*)(smem + w*18432 + 9216);
  unsigned short* tB1 = (unsigned short*)(smem + w*18432 + 13824);
  f32x4 Wacc[4][4], Gacc[4][4];
  #pragma unroll
  for (int i = 0; i < 4; ++i)
    #pragma unroll
    for (int j = 0; j < 4; ++j) { Wacc[i][j] = (f32x4)(0.f); Gacc[i][j] = (f32x4)(0.f); }

  // ---- phase 1: write GEMM, K slice [w*128, w*128+128), 4 iters ----
  {
    const unsigned short* arow = Wt  + (size_t)b*kSlots*kTok + (size_t)lane*kTok + w*128;
    const unsigned short* brow = VtT + (size_t)b*kDim*kTok + (size_t)(n0+lane)*kTok + w*128;
    u16x8 pa[4], pb[4];
    #pragma unroll
    for (int h = 0; h < 4; ++h) {
      pa[h] = *reinterpret_cast<const u16x8*>(arow + 8*h);
      pb[h] = *reinterpret_cast<const u16x8*>(brow + 8*h);
    }
    #pragma unroll
    for (int h = 0; h < 4; ++h) {
      *reinterpret_cast<u16x8*>(tA0 + lane*kPad2 + 8*h) = pa[h];
      *reinterpret_cast<u16x8*>(tB0 + lane*kPad2 + 8*h) = pb[h];
    }
    #pragma unroll
    for (int h = 0; h < 4; ++h) {
      pa[h] = *reinterpret_cast<const u16x8*>(arow + 32 + 8*h);
      pb[h] = *reinterpret_cast<const u16x8*>(brow + 32 + 8*h);
    }
    #pragma unroll
    for (int i = 0; i < 4; ++i) {
      unsigned short* cA = (i & 1) ? tA1 : tA0;
      unsigned short* cB = (i & 1) ? tB1 : tB0;
      if (i < 3) {
        unsigned short* nA = (i & 1) ? tA0 : tA1;
        unsigned short* nB = (i & 1) ? tB0 : tB1;
        #pragma unroll
        for (int h = 0; h < 4; ++h) {
          *reinterpret_cast<u16x8*>(nA + lane*kPad2 + 8*h) = pa[h];
          *reinterpret_cast<u16x8*>(nB + lane*kPad2 + 8*h) = pb[h];
        }
        if (i < 2) {
          #pragma unroll
          for (int h = 0; h < 4; ++h) {
            pa[h] = *reinterpret_cast<const u16x8*>(arow + (i+2)*32 + 8*h);
            pb[h] = *reinterpret_cast<const u16x8*>(brow + (i+2)*32 + 8*h);
          }
        }
      }
      bf16x8 a[4], bbv[4];
      #pragma unroll
      for (int mt = 0; mt < 4; ++mt) a[mt] = *reinterpret_cast<const bf16x8*>(cA + (mt*16 + fr)*kPad2 + kg);
      #pragma unroll
      for (int nt = 0; nt < 4; ++nt) bbv[nt] = *reinterpret_cast<const bf16x8*>(cB + (nt*16 + fr)*kPad2 + kg);
      #pragma unroll
      for (int mt = 0; mt < 4; ++mt)
        #pragma unroll
        for (int nt = 0; nt < 4; ++nt)
          Wacc[mt][nt] = __builtin_amdgcn_mfma_f32_16x16x32_bf16(a[mt], bbv[nt], Wacc[mt][nt], 0, 0, 0);
    }
  }
  // ---- phase 2: gate GEMM, K slice [w*192, w*192+192), 6 iters ----
  {
    const unsigned short* arow = MbIn + (size_t)(b*kSlots + lane)*kDim + w*192;
    const unsigned short* brow = gWT + (size_t)(n0 + lane)*kDim + w*192;
    u16x8 pa[4], pb[4];
    #pragma unroll
    for (int h = 0; h < 4; ++h) {
      pa[h] = *reinterpret_cast<const u16x8*>(arow + 8*h);
      pb[h] = *reinterpret_cast<const u16x8*>(brow + 8*h);
    }
    #pragma unroll
    for (int h = 0; h < 4; ++h) {
      *reinterpret_cast<u16x8*>(tA0 + lane*kPad2 + 8*h) = pa[h];
      *reinterpret_cast<u16x8*>(tB0 + lane*kPad2 + 8*h) = pb[h];
    }
    #pragma unroll
    for (int h = 0; h < 4; ++h) {
      pa[h] = *reinterpret_cast<const u16x8*>(arow + 32 + 8*h);
      pb[h] = *reinterpret_cast<const u16x8*>(brow + 32 + 8*h);
    }
    #pragma unroll
    for (int i = 0; i < 6; ++i) {
      unsigned short* cA = (i & 1) ? tA1 : tA0;
      unsigned short* cB = (i & 1) ? tB1 : tB0;
      if (i < 5) {
        unsigned short* nA = (i & 1) ? tA0 : tA1;
        unsigned short* nB = (i & 1) ? tB0 : tB1;
        #pragma unroll
        for (int h = 0; h < 4; ++h) {
          *reinterpret_cast<u16x8*>(nA + lane*kPad2 + 8*h) = pa[h];
          *reinterpret_cast<u16x8*>(nB + lane*kPad2 + 8*h) = pb[h];
        }
        if (i < 4) {
          #pragma unroll
          for (int h = 0; h < 4; ++h) {
            pa[h] = *reinterpret_cast<const u16x8*>(arow + (i+2)*32 + 8*h);
            pb[h] = *reinterpret_cast<const u16x8*>(brow + (i+2)*32 + 8*h);
          }
        }
      }
      bf16x8 a[4], bbv[4];
      #pragma unroll
      for (int mt = 0; mt < 4; ++mt) a[mt] = *reinterpret_cast<const bf16x8*>(cA + (mt*16 + fr)*kPad2 + kg);
      #pragma unroll
      for (int nt = 0; nt < 4; ++nt) bbv[nt] = *reinterpret_cast<const bf16x8*>(cB + (nt*16 + fr)*kPad2 + kg);
      #pragma unroll
      for (int mt = 0; mt < 4; ++mt)
        #pragma unroll
        for (int nt = 0; nt < 4; ++nt)
          Gacc[mt][nt] = __builtin_amdgcn_mfma_f32_16x16x32_bf16(a[mt], bbv[nt], Gacc[mt][nt], 0, 0, 0);
    }
  }
  // ---- reduction: WA=w0+w1, WB=w2+w3, GA=g0+g1, GB=g2+g3 ----
  __syncthreads();
  float (*WA)[65] = (float(*)[65])(smem);
  float (*WB)[65] = (float(*)[65])(smem + 16640);
  float (*GA)[65] = (float(*)[65])(smem + 33280);
  float (*GB)[65] = (float(*)[65])(smem + 49920);
  if (w == 1) {
    #pragma unroll
    for (int mt = 0; mt < 4; ++mt)
      #pragma unroll
      for (int nt = 0; nt < 4; ++nt)
        #pragma unroll
        for (int r = 0; r < 4; ++r) WA[mt*16 + crow + r][nt*16 + fr] = Wacc[mt][nt][r];
  } else if (w == 3) {
    #pragma unroll
    for (int mt = 0; mt < 4; ++mt)
      #pragma unroll
      for (int nt = 0; nt < 4; ++nt)
        #pragma unroll
        for (int r = 0; r < 4; ++r) WB[mt*16 + crow + r][nt*16 + fr] = Wacc[mt][nt][r];
  } else if (w == 0) {
    #pragma unroll
    for (int mt = 0; mt < 4; ++mt)
      #pragma unroll
      for (int nt = 0; nt < 4; ++nt)
        #pragma unroll
        for (int r = 0; r < 4; ++r) GA[mt*16 + crow + r][nt*16 + fr] = Gacc[mt][nt][r];
  } else {
    #pragma unroll
    for (int mt = 0; mt < 4; ++mt)
      #pragma unroll
      for (int nt = 0; nt < 4; ++nt)
        #pragma unroll
        for (int r = 0; r < 4; ++r) GB[mt*16 + crow + r][nt*16 + fr] = Gacc[mt][nt][r];
  }
  __syncthreads();
  if (w == 0) {
    #pragma unroll
    for (int mt = 0; mt < 4; ++mt)
      #pragma unroll
      for (int nt = 0; nt < 4; ++nt)
        #pragma unroll
        for (int r = 0; r < 4; ++r) WA[mt*16 + crow + r][nt*16 + fr] += Wacc[mt][nt][r];
  } else if (w == 2) {
    #pragma unroll
    for (int mt = 0; mt < 4; ++mt)
      #pragma unroll
      for (int nt = 0; nt < 4; ++nt)
        #pragma unroll
        for (int r = 0; r < 4; ++r) WB[mt*16 + crow + r][nt*16 + fr] += Wacc[mt][nt][r];
  } else if (w == 1) {
    #pragma unroll
    for (int mt = 0; mt < 4; ++mt)
      #pragma unroll
      for (int nt = 0; nt < 4; ++nt)
        #pragma unroll
        for (int r = 0; r < 4; ++r) GA[mt*16 + crow + r][nt*16 + fr] += Gacc[mt][nt][r];
  } else {
    #pragma unroll
    for (int mt = 0; mt < 4; ++mt)
      #pragma unroll
      for (int nt = 0; nt < 4; ++nt)
        #pragma unroll
        for (int r = 0; r < 4; ++r) GB[mt*16 + crow + r][nt*16 + fr] += Gacc[mt][nt][r];
  }
  __syncthreads();
  // ---- epilogue: wave w handles s rows [w*16, w*16+16) ----
  #pragma unroll
  for (int r = 0; r < 16; ++r) {
    const int s = w*16 + r;
    const float wf = WA[s][lane] + WB[s][lane];
    const float gf = GA[s][lane] + GB[s][lane];
    const float z = gf + gb[n0 + lane];
    const float g = 1.f / (1.f + __expf(-z));
    const size_t off = (size_t)(b*kSlots + s) * kDim + n0 + lane;
    const float mn = clipf(0.9f * M[off] + 0.1f * g * wf, 50.f);
    M[off] = mn;
    MbOut[off] = f2bf(mn);
  }
}

// ---------------- final pooling + LN + classifier ------------------------------
__global__ __launch_bounds__(256) void k_final(
    const unsigned short* __restrict__ Wt, const float* __restrict__ M,
    const int* __restrict__ mask, const float* __restrict__ vf,
    const float* __restrict__ lng, const float* __restrict__ lnb,
    const float* __restrict__ clsW, const float* __restrict__ clsb,
    float* __restrict__ out)
{
  __shared__ float red[256];
  __shared__ float wsum[kSlots];
  __shared__ float pooled[kDim];
  __shared__ float sh_mu, sh_var;
  const int b = blockIdx.x, tid = threadIdx.x;
  const unsigned short* wb = Wt + (size_t)b * kSlots * kTok;

  {
    const int s = tid & 63, q = tid >> 6;
    const unsigned short* wr = wb + (size_t)s * kTok + q * 128;
    const int* mrow = mask + b * kTok + q * 128;
    float p = 0.f;
    #pragma unroll 4
    for (int j = 0; j < 16; ++j) {
      u16x8 v = *reinterpret_cast<const u16x8*>(wr + 8*j);
      #pragma unroll
      for (int e = 0; e < 8; ++e)
        if (mrow[8*j + e] > 0) p += bf2f(v[e]);
    }
    red[tid] = p;
  }
  __syncthreads();
  if (tid < 64) wsum[tid] = red[tid] + red[tid+64] + red[tid+128] + red[tid+192];
  __syncthreads();

  const float denom = fmaxf(vf[b], 1.f);
  for (int d = tid; d < kDim; d += 256) {
    float acc = 0.f;
    const float* Mb2 = M + (size_t)(b*kSlots) * kDim + d;
    #pragma unroll 4
    for (int s = 0; s < kSlots; ++s) acc += wsum[s] * Mb2[(size_t)s * kDim];
    pooled[d] = acc / denom;
  }
  __syncthreads();

  float lp = 0.f;
  for (int d = tid; d < kDim; d += 256) lp += pooled[d];
  red[tid] = lp; __syncthreads();
  for (int off = 128; off > 0; off >>= 1) { if (tid < off) red[tid] += red[tid+off]; __syncthreads(); }
  if (tid == 0) sh_mu = red[0] / kDim;
  __syncthreads();
  const float mu = sh_mu;
  float lv = 0.f;
  for (int d = tid; d < kDim; d += 256) { float z = pooled[d] - mu; lv += z*z; }
  red[tid] = lv; __syncthreads();
  for (int off = 128; off > 0; off >>= 1) { if (tid < off) red[tid] += red[tid+off]; __syncthreads(); }
  if (tid == 0) sh_var = red[0] / kDim;
  __syncthreads();
  const float inv = rsqrtf(sh_var + 1e-5f);
  for (int d = tid; d < kDim; d += 256)
    pooled[d] = (pooled[d] - mu) * inv * lng[d] + lnb[d];
  __syncthreads();

  {
    const int c = tid & 7, dg = tid >> 3;
    float part = 0.f;
    for (int d = dg; d < kDim; d += 32) part += pooled[d] * clsW[(size_t)d * kCls + c];
    red[tid] = part;
  }
  __syncthreads();
  if (tid < 8) {
    float s = clsb[tid];
    #pragma unroll
    for (int dg = 0; dg < 32; ++dg) s += red[dg*8 + tid];
    if (!isfinite(s)) s = 0.f;
    out[b*kCls + tid] = s;
  }
}

}  // namespace

extern "C" void kernel_launch(void* const* d_in, const int* in_sizes, int n_in,
                              void* d_out, int out_size, void* d_ws, size_t ws_size,
                              hipStream_t stream)
{
  const int*   ids = (const int*)  d_in[0];
  const int*   msk = (const int*)  d_in[1];
  const float* tok = (const float*)d_in[2];
  const float* pos = (const float*)d_in[3];
  const float* Wq  = (const float*)d_in[4];
  const float* Wk  = (const float*)d_in[5];
  const float* Wv  = (const float*)d_in[6];
  const float* gW  = (const float*)d_in[7];
  const float* gb  = (const float*)d_in[8];
  const float* lng = (const float*)d_in[9];
  const float* lnb = (const float*)d_in[10];
  const float* cW  = (const float*)d_in[11];
  const float* cb  = (const float*)d_in[12];
  const float* mi  = (const float*)d_in[13];
  float* out = (float*)d_out;
  char* base = (char*)d_ws;

  size_t off = 0;
  unsigned short* Qk   = (unsigned short*)(base + off); off += (size_t)kBatch*kTok*kDim*2;
  unsigned short* VtT  = (unsigned short*)(base + off); off += (size_t)kBatch*kDim*kTok*2;
  unsigned short* Wt   = (unsigned short*)(base + off); off += (size_t)kBatch*kSlots*kTok*2;
  unsigned short* WvT  = (unsigned short*)(base + off); off += (size_t)kDim*kDim*2;
  unsigned short* gWT  = (unsigned short*)(base + off); off += (size_t)kDim*kDim*2;
  unsigned short* WqkT = (unsigned short*)(base + off); off += (size_t)kDim*kDim*2;
  float* M   = (float*)(base + off);          off += (size_t)kBatch*kSlots*kDim*4;
  unsigned short* Mb0 = (unsigned short*)(base + off); off += (size_t)kBatch*kSlots*kDim*2;
  unsigned short* Mb1 = (unsigned short*)(base + off); off += (size_t)kBatch*kSlots*kDim*2;
  float* vf  = (float*)(base + off);          off += 256;

  k_prep<<<dim3(kDim/32, kDim/32, 2), 256, 0, stream>>>(Wv, gW, WvT, gWT);
  k_wqk<<<dim3(kDim/64, kDim/64), 64, 0, stream>>>(Wk, Wq, WqkT);
  k_minit<<<dim3((kBatch*kSlots*kDim/4)/256), 256, 0, stream>>>(mi, M, Mb0);
  k_valid<<<dim3(kBatch), 256, 0, stream>>>(msk, vf);
  k_embed_qv<<<dim3(kBatch*kTok/64, kDim/128), 256, 0, stream>>>(ids, tok, pos, WqkT, WvT, Qk, VtT);
  unsigned short* mcur = Mb0;
  unsigned short* mnext = Mb1;
  for (int it = 0; it < kSteps; ++it) {
    k_scores<<<dim3(kTok/32, kBatch), 128, 0, stream>>>(Qk, mcur, msk, vf, Wt);
    k_write_gate<<<dim3(kDim/64, kBatch), 256, 0, stream>>>(Wt, VtT, mcur, gWT, gb, M, mnext);
    unsigned short* t = mcur; mcur = mnext; mnext = t;
  }
  k_scores<<<dim3(kTok/32, kBatch), 128, 0, stream>>>(Qk, mcur, msk, vf, Wt);
  k_final<<<dim3(kBatch), 256, 0, stream>>>(Wt, M, msk, vf, lng, lnb, cW, cb, out);

  (void)in_sizes; (void)n_in; (void)out_size; (void)ws_size;
}